// Round 10
// baseline (577.583 us; speedup 1.0000x reference)
//
#include <hip/hip_runtime.h>
#include <math.h>

#define N_NODES 50000
#define N_EDGES 800000
#define DIM 128
#define SCAN_BLOCKS 49      // 49*1024 = 50176 >= 50001

typedef __attribute__((ext_vector_type(8))) short short8;
typedef __attribute__((ext_vector_type(4))) float floatx4;

// f32 -> bf16 bits, round-to-nearest-even (matches v_cvt / numpy)
__device__ __forceinline__ unsigned short f32_to_bf16(float f) {
    unsigned int u = __float_as_uint(f);
    u += 0x7fffu + ((u >> 16) & 1u);
    return (unsigned short)(u >> 16);
}
__device__ __forceinline__ float bf16_to_f32(unsigned short h) {
    return __uint_as_float((unsigned int)h << 16);
}

// ---------------- CSR build ----------------

__global__ __launch_bounds__(256) void hist_kernel(const int* __restrict__ dst,
                                                   int* __restrict__ deg) {
    int e = blockIdx.x * 256 + threadIdx.x;
    if (e < N_EDGES) atomicAdd(&deg[dst[e]], 1);
}

__global__ __launch_bounds__(1024) void scan1(const int* __restrict__ deg,
                                              int* __restrict__ rowp,
                                              int* __restrict__ part) {
    __shared__ int buf[1024];
    int i = blockIdx.x * 1024 + threadIdx.x;
    int v = (i < N_NODES) ? deg[i] : 0;
    buf[threadIdx.x] = v;
    __syncthreads();
    for (int off = 1; off < 1024; off <<= 1) {
        int t = (threadIdx.x >= (unsigned)off) ? buf[threadIdx.x - off] : 0;
        __syncthreads();
        buf[threadIdx.x] += t;
        __syncthreads();
    }
    if (i < N_NODES) rowp[i] = buf[threadIdx.x] - v;   // local exclusive
    if (threadIdx.x == 1023) part[blockIdx.x] = buf[1023];
}

__global__ void scan2(int* __restrict__ part) {        // 1 block, 64 threads
    int v = (threadIdx.x < SCAN_BLOCKS) ? part[threadIdx.x] : 0;
    for (int off = 1; off < 64; off <<= 1) {
        int t = __shfl_up(v, off);
        if ((int)threadIdx.x >= off) v += t;
    }
    if (threadIdx.x < SCAN_BLOCKS) part[threadIdx.x] = v;   // inclusive totals
}

__global__ __launch_bounds__(1024) void scan3(int* __restrict__ rowp,
                                              int* __restrict__ cursor,
                                              const int* __restrict__ part) {
    int i = blockIdx.x * 1024 + threadIdx.x;
    int off = (blockIdx.x > 0) ? part[blockIdx.x - 1] : 0;
    if (i < N_NODES) {
        int r = rowp[i] + off;
        rowp[i] = r;
        cursor[i] = r;
    }
    if (i == N_NODES) rowp[N_NODES] = part[SCAN_BLOCKS - 1];  // == N_EDGES
}

// single-pass scatter; non-temporal store to avoid 8-XCD dirty-line blowup
__global__ __launch_bounds__(256) void scatter_kernel(const int* __restrict__ src,
                                                      const int* __restrict__ dst,
                                                      const float* __restrict__ ew,
                                                      int* __restrict__ cursor,
                                                      int2* __restrict__ ep) {
    int e = blockIdx.x * 256 + threadIdx.x;
    if (e < N_EDGES) {
        int d = dst[e];
        int pos = atomicAdd(&cursor[d], 1);
        int2 p; p.x = src[e]; p.y = __float_as_int(ew[e]);
        long long pv;
        __builtin_memcpy(&pv, &p, 8);
        __builtin_nontemporal_store(pv, (long long*)(ep + pos));
    }
}

// ---------------- per-layer W' transpose prep ----------------
// WT[l][n][k] = bf16( beta_l*W[l][k][n] + (1-beta_l)*delta(n,k) )

__global__ __launch_bounds__(256) void prep_wt(const float* __restrict__ Wcv,
                                               unsigned short* __restrict__ WTall) {
    int l = blockIdx.x;
    float beta = logf(0.5f / (float)(l + 1) + 1.f);
    float cm = 1.f - beta, cg = beta;
    const float* W = Wcv + (size_t)l * DIM * DIM;
    unsigned short* WT = WTall + (size_t)l * DIM * DIM;
    for (int idx = threadIdx.x; idx < DIM * DIM; idx += 256) {
        int k = idx >> 7, n = idx & 127;
        WT[n * DIM + k] = f32_to_bf16(cg * W[idx] + ((n == k) ? cm : 0.f));
    }
}

// ---------------- fused layer: spmm + residual-mix + MFMA gemm --------------
// Block = 16 nodes, 256 threads (4 waves). Phase 1: wave w runs the spmm7
// gather loop (ILP-4, edge groups) for nodes w*4..w*4+3, mixes with x0, and
// writes bf16 m rows to LDS (m never touches HBM). Phase 2: each wave MFMAs
// a 32-col strip: A-frags from LDS, B-frags from the L2-hot precomputed W'T.
// out = relu(m @ ((1-b)I + b*W)) written as bf16 rows (next h) or f32 (final).

__global__ __launch_bounds__(256) void layer_fused(const unsigned short* __restrict__ hB,
                                                   const unsigned short* __restrict__ x0B,
                                                   const int* __restrict__ rowp,
                                                   const int2* __restrict__ ep,
                                                   const unsigned short* __restrict__ WT,
                                                   float* __restrict__ outF,
                                                   unsigned short* __restrict__ outB) {
    __shared__ unsigned short M[16][136];
    int wave = threadIdx.x >> 6;
    int lane = threadIdx.x & 63;
    int eg = lane >> 4;                               // edge group 0..3
    int fb = (lane & 15) * 8;                         // feature octet
    int nodeBase = blockIdx.x * 16;

    // ---- phase 1: spmm for 4 nodes per wave ----
    for (int t = 0; t < 4; t++) {
        int nl = wave * 4 + t;
        int node = nodeBase + nl;
        int beg = rowp[node], end = rowp[node + 1];
        float acc[8] = {0.f, 0.f, 0.f, 0.f, 0.f, 0.f, 0.f, 0.f};
        if (beg < end) {
            int last = end - 1;
            for (int i = beg; i < end; i += 16) {
                int i0 = i + eg, i1 = i0 + 4, i2 = i0 + 8, i3 = i0 + 12;
                int2 e0 = ep[min(i0, last)];
                int2 e1 = ep[min(i1, last)];
                int2 e2 = ep[min(i2, last)];
                int2 e3 = ep[min(i3, last)];
                short8 r0 = *(const short8*)(const void*)(hB + (size_t)e0.x * DIM + fb);
                short8 r1 = *(const short8*)(const void*)(hB + (size_t)e1.x * DIM + fb);
                short8 r2 = *(const short8*)(const void*)(hB + (size_t)e2.x * DIM + fb);
                short8 r3 = *(const short8*)(const void*)(hB + (size_t)e3.x * DIM + fb);
                float w0 = (i0 < end) ? __int_as_float(e0.y) : 0.f;
                float w1 = (i1 < end) ? __int_as_float(e1.y) : 0.f;
                float w2 = (i2 < end) ? __int_as_float(e2.y) : 0.f;
                float w3 = (i3 < end) ? __int_as_float(e3.y) : 0.f;
#pragma unroll
                for (int j = 0; j < 8; j++) {
                    acc[j] = fmaf(w0, bf16_to_f32((unsigned short)r0[j]), acc[j]);
                    acc[j] = fmaf(w1, bf16_to_f32((unsigned short)r1[j]), acc[j]);
                    acc[j] = fmaf(w2, bf16_to_f32((unsigned short)r2[j]), acc[j]);
                    acc[j] = fmaf(w3, bf16_to_f32((unsigned short)r3[j]), acc[j]);
                }
            }
        }
#pragma unroll
        for (int j = 0; j < 8; j++) {
            acc[j] += __shfl_down(acc[j], 32);
            acc[j] += __shfl_down(acc[j], 16);
        }
        if (lane < 16) {
            short8 xv = *(const short8*)(const void*)(x0B + (size_t)(nodeBase + nl) * DIM + fb);
            short8 o;
#pragma unroll
            for (int j = 0; j < 8; j++)
                o[j] = (short)f32_to_bf16(0.9f * acc[j]
                                          + 0.1f * bf16_to_f32((unsigned short)xv[j]));
            *(short8*)(void*)(&M[nl][fb]) = o;
        }
    }
    __syncthreads();

    // ---- phase 2: gemm, wave covers cols wave*32 .. wave*32+31 ----
    int mrow = lane & 15;
    int quad = lane >> 4;
    floatx4 acc2[2];
    acc2[0] = {0.f, 0.f, 0.f, 0.f};
    acc2[1] = {0.f, 0.f, 0.f, 0.f};
#pragma unroll
    for (int k0 = 0; k0 < 128; k0 += 32) {
        short8 a = *(const short8*)(const void*)(&M[mrow][k0 + quad * 8]);
#pragma unroll
        for (int t = 0; t < 2; t++) {
            int col = wave * 32 + t * 16 + mrow;
            short8 b = *(const short8*)(const void*)(WT + (size_t)col * DIM + k0 + quad * 8);
            acc2[t] = __builtin_amdgcn_mfma_f32_16x16x32_bf16(a, b, acc2[t], 0, 0, 0);
        }
    }
    // C/D layout: col = lane&15, row = quad*4 + i  [verified m89/m91]
#pragma unroll
    for (int t = 0; t < 2; t++) {
        int col = wave * 32 + t * 16 + mrow;
#pragma unroll
        for (int i = 0; i < 4; i++) {
            int row = nodeBase + quad * 4 + i;
            size_t off = (size_t)row * DIM + col;
            float v = fmaxf(acc2[t][i], 0.f);
            if (outF) outF[off] = v;
            if (outB) outB[off] = f32_to_bf16(v);
        }
    }
}

// ---------------- MFMA GEMM (layer-0 lins only): relu(x@Wlin + b) -----------

__global__ __launch_bounds__(256) void gemm128(const float* __restrict__ A,
                                               const float* __restrict__ W,
                                               const float* __restrict__ bias,
                                               unsigned short* __restrict__ outB) {
    __shared__ unsigned short WTs[128][136];
    for (int idx = threadIdx.x; idx < 128 * 128; idx += 256) {
        int k = idx >> 7, n = idx & 127;
        WTs[n][k] = f32_to_bf16(W[idx]);
    }
    __syncthreads();

    int wave = threadIdx.x >> 6;
    int lane = threadIdx.x & 63;
    int r0 = (blockIdx.x * 4 + wave) * 16;
    if (r0 >= N_NODES) return;

    int mrow = lane & 15;
    int quad = lane >> 4;

    floatx4 acc[8];
#pragma unroll
    for (int t = 0; t < 8; t++) acc[t] = {0.f, 0.f, 0.f, 0.f};

    const float* arow = A + (size_t)(r0 + mrow) * DIM;
#pragma unroll
    for (int k0 = 0; k0 < 128; k0 += 32) {
        floatx4 alo = *(const floatx4*)(const void*)(arow + k0 + quad * 8);
        floatx4 ahi = *(const floatx4*)(const void*)(arow + k0 + quad * 8 + 4);
        short8 a;
#pragma unroll
        for (int j = 0; j < 4; j++) a[j] = (short)f32_to_bf16(alo[j]);
#pragma unroll
        for (int j = 0; j < 4; j++) a[4 + j] = (short)f32_to_bf16(ahi[j]);
#pragma unroll
        for (int t = 0; t < 8; t++) {
            short8 b = *(const short8*)(const void*)(&WTs[t * 16 + mrow][k0 + quad * 8]);
            acc[t] = __builtin_amdgcn_mfma_f32_16x16x32_bf16(a, b, acc[t], 0, 0, 0);
        }
    }

#pragma unroll
    for (int t = 0; t < 8; t++) {
        int col = t * 16 + mrow;
        float bv = bias[col];
#pragma unroll
        for (int i = 0; i < 4; i++) {
            int row = r0 + quad * 4 + i;
            float v = fmaxf(acc[t][i] + bv, 0.f);
            outB[(size_t)row * DIM + col] = f32_to_bf16(v);
        }
    }
}

// ---------------- launch ----------------

extern "C" void kernel_launch(void* const* d_in, const int* in_sizes, int n_in,
                              void* d_out, int out_size, void* d_ws, size_t ws_size,
                              hipStream_t stream) {
    const float* x    = (const float*)d_in[0];
    const float* ew   = (const float*)d_in[1];
    const float* Wlin = (const float*)d_in[2];
    const float* blin = (const float*)d_in[3];
    const float* Wcv  = (const float*)d_in[4];
    const int* eidx = (const int*)d_in[5];
    const int* esrc = eidx;
    const int* edst = eidx + N_EDGES;
    float* out = (float*)d_out;

    char* ws = (char*)d_ws;
    unsigned short* x0B  = (unsigned short*)(ws);             // 12.8 MB bf16 x0 rows
    unsigned short* h0   = (unsigned short*)(ws + 12800000);  // 12.8 MB bf16 h rows (even layers out)
    unsigned short* h1   = (unsigned short*)(ws + 25600000);  // 12.8 MB bf16 h rows (odd layers out)
    int* rowp            = (int*)(ws + 38400000);             // (N+1)*4
    int* cursor          = (int*)(ws + 38600064);             // also 'deg'
    int2* epack          = (int2*)(ws + 38800128);            // E*8
    int* part            = (int*)(ws + 45200128);             // scan partials
    unsigned short* WTall= (unsigned short*)(ws + 45200512);  // 8*128*128 bf16 = 256 KB
    // total ~45.5 MB

    // CSR build (every call; no static state)
    (void)hipMemsetAsync(cursor, 0, (N_NODES + 1) * sizeof(int), stream);
    hist_kernel<<<(N_EDGES + 255) / 256, 256, 0, stream>>>(edst, cursor);
    scan1<<<SCAN_BLOCKS, 1024, 0, stream>>>(cursor, rowp, part);
    scan2<<<1, 64, 0, stream>>>(part);
    scan3<<<SCAN_BLOCKS, 1024, 0, stream>>>(rowp, cursor, part);
    scatter_kernel<<<(N_EDGES + 255) / 256, 256, 0, stream>>>(esrc, edst, ew, cursor, epack);
    prep_wt<<<8, 256, 0, stream>>>(Wcv, WTall);

    // x0 = relu(x @ W_lin + b_lin) -> bf16 rows
    gemm128<<<(N_NODES + 63) / 64, 256, 0, stream>>>(x, Wlin, blin, x0B);

    const unsigned short* hin = x0B;
    for (int l = 0; l < 8; l++) {
        unsigned short* hout = (l & 1) ? h1 : h0;
        layer_fused<<<N_NODES / 16, 256, 0, stream>>>(hin, x0B, rowp, epack,
                                                      WTall + (size_t)l * DIM * DIM,
                                                      (l == 7) ? out : nullptr,
                                                      (l < 7) ? hout : nullptr);
        hin = hout;
    }
}